// Round 1
// baseline (1551.772 us; speedup 1.0000x reference)
//
#include <hip/hip_runtime.h>
#include <hip/hip_bf16.h>
#include <stdint.h>

// Problem constants (fixed by setup_inputs)
#define BATCH   16
#define DIM     256        // embedding dim / channels
#define HWSZ    4096       // 64*64
#define N_ROWS  65536      // BATCH * HWSZ
#define KCB     1024       // codebook entries
#define Q_ELEMS 16777216   // BATCH*DIM*HWSZ
#define COMMIT_COST 0.25f

// GEMM tiling
#define MT 128             // rows per block
#define NT 128             // codebook cols per k-chunk
#define CC 16              // channels per staged chunk
#define KD 48              // 3 sections * CC rows in LDS per chunk

// ws float-offsets
#define WS_BC    0                       // [768*1024]
#define WS_BIAS  (768*1024)              // [1024]
#define WS_IDX   (WS_BIAS + KCB)         // [65536] int32
#define WS_LOSS  (WS_IDX + N_ROWS)       // [1] f32

// ---------------------------------------------------------------------------
// Build combined B matrix [768][1024]:
//   row j<256      : -4*e^3   (pairs with x)
//   row 256..511   :  6*e^2   (pairs with x^2)
//   row 512..767   : -4*e     (pairs with x^3)
// and bias[k] = sum_d e^4. Also zero the loss accumulator.
__global__ void prep_embed(const float* __restrict__ embed, float* __restrict__ Bc,
                           float* __restrict__ bias, float* __restrict__ loss_accum) {
    const int k = blockIdx.x;
    const int t = threadIdx.x;
    const float e  = embed[k * DIM + t];
    const float e2 = e * e;
    const float e3 = e2 * e;
    const float e4 = e2 * e2;
    Bc[t * KCB + k]             = -4.f * e3;
    Bc[(DIM + t) * KCB + k]     =  6.f * e2;
    Bc[(2 * DIM + t) * KCB + k] = -4.f * e;

    float s = e4;
    #pragma unroll
    for (int o = 32; o > 0; o >>= 1) s += __shfl_down(s, o, 64);
    __shared__ float ps[4];
    if ((t & 63) == 0) ps[t >> 6] = s;
    __syncthreads();
    if (t == 0) {
        bias[k] = ps[0] + ps[1] + ps[2] + ps[3];
        if (k == 0) *loss_accum = 0.f;
    }
}

// ---------------------------------------------------------------------------
// Fused distance-GEMM + running argmin.
// Block: 256 threads, 128 rows x (all 1024 cols in chunks of 128).
// A is read from inputs[b][c][hw] (contiguous along hw) and x^2/x^3 are
// generated during staging (1x global traffic for 3 sections).
__launch_bounds__(256, 3)
__global__ void dist_argmin(const float* __restrict__ x, const float* __restrict__ Bc,
                            const float* __restrict__ bias, int* __restrict__ out_idx) {
    __shared__ float As[KD * MT];   // 24 KB
    __shared__ float Bs[KD * NT];   // 24 KB

    const int t   = threadIdx.x;
    const int n0  = blockIdx.x * MT;
    const int b   = n0 >> 12;        // 4096 rows per batch image
    const int hw0 = n0 & (HWSZ - 1);
    const int tx  = t & 15;
    const int ty  = t >> 4;

    const float* xb = x + (((size_t)b) << 20) + hw0;  // + (c<<12) + m per element

    float rminv[8];
    int   rmini[8];
    #pragma unroll
    for (int m = 0; m < 8; ++m) { rminv[m] = __builtin_inff(); rmini[m] = 0; }

    #pragma unroll 1
    for (int kc = 0; kc < KCB / NT; ++kc) {
        float acc[8][8];
        #pragma unroll
        for (int m = 0; m < 8; ++m)
            #pragma unroll
            for (int j = 0; j < 8; ++j) acc[m][j] = 0.f;

        #pragma unroll 1
        for (int cc = 0; cc < DIM / CC; ++cc) {
            // ---- stage A chunk: 16 channels x 128 rows, powers on the fly
            #pragma unroll
            for (int i = 0; i < 2; ++i) {
                const int ci = i * 8 + (t >> 5);     // 0..15
                const int m4 = (t & 31) << 2;        // 0..124
                const float4 v = *(const float4*)(xb + (((size_t)(cc * CC + ci)) << 12) + m4);
                float4 v2, v3;
                v2.x = v.x * v.x; v2.y = v.y * v.y; v2.z = v.z * v.z; v2.w = v.w * v.w;
                v3.x = v2.x * v.x; v3.y = v2.y * v.y; v3.z = v2.z * v.z; v3.w = v2.w * v.w;
                *(float4*)&As[ci * MT + m4]            = v;
                *(float4*)&As[(CC + ci) * MT + m4]     = v2;
                *(float4*)&As[(2 * CC + ci) * MT + m4] = v3;
            }
            // ---- stage B chunk: 48 rows x 128 cols
            const float* Bg = Bc + kc * NT;
            #pragma unroll
            for (int i = 0; i < 6; ++i) {
                const int r  = i * 8 + (t >> 5);     // 0..47
                const int k4 = (t & 31) << 2;
                const int s  = r >> 4;               // section
                const int ci = r & 15;
                const float4 bv = *(const float4*)(Bg + ((size_t)(s * DIM + cc * CC + ci)) * KCB + k4);
                *(float4*)&Bs[r * NT + k4] = bv;
            }
            __syncthreads();

            // ---- 48-deep outer-product accumulate
            #pragma unroll 8
            for (int dd = 0; dd < KD; ++dd) {
                const float4 a0 = *(const float4*)&As[dd * MT + ty * 8];
                const float4 a1 = *(const float4*)&As[dd * MT + ty * 8 + 4];
                const float4 b0 = *(const float4*)&Bs[dd * NT + tx * 8];
                const float4 b1 = *(const float4*)&Bs[dd * NT + tx * 8 + 4];
                const float av[8] = {a0.x, a0.y, a0.z, a0.w, a1.x, a1.y, a1.z, a1.w};
                const float bv[8] = {b0.x, b0.y, b0.z, b0.w, b1.x, b1.y, b1.z, b1.w};
                #pragma unroll
                for (int m = 0; m < 8; ++m)
                    #pragma unroll
                    for (int j = 0; j < 8; ++j)
                        acc[m][j] += av[m] * bv[j];
            }
            __syncthreads();
        }

        // ---- argmin update for this k-chunk
        float bb[8];
        #pragma unroll
        for (int j = 0; j < 8; ++j) bb[j] = bias[kc * NT + tx * 8 + j];
        #pragma unroll
        for (int m = 0; m < 8; ++m) {
            #pragma unroll
            for (int j = 0; j < 8; ++j) {
                const float v  = acc[m][j] + bb[j];
                const int   ki = kc * NT + tx * 8 + j;
                if (v < rminv[m]) { rminv[m] = v; rmini[m] = ki; }  // strict <: first occurrence
            }
        }
    }

    // ---- reduce across the 16 lanes sharing each row (lexicographic min)
    #pragma unroll
    for (int m = 0; m < 8; ++m) {
        float v = rminv[m];
        int   i = rmini[m];
        #pragma unroll
        for (int o = 1; o < 16; o <<= 1) {
            const float ov = __shfl_xor(v, o, 64);
            const int   oi = __shfl_xor(i, o, 64);
            if (ov < v || (ov == v && oi < i)) { v = ov; i = oi; }
        }
        if (tx == 0) out_idx[n0 + ty * 8 + m] = i;
    }
}

// ---------------------------------------------------------------------------
// Gather quantized vectors back to [B,C,H,W], compute straight-through output
// exactly as the reference (x + (q - x)), accumulate commitment loss, and
// emit indices as floats.
__global__ void gather_out(const float* __restrict__ x, const float* __restrict__ embed,
                           const int* __restrict__ idx, float* __restrict__ out,
                           float* __restrict__ loss_accum) {
    const int tid = blockIdx.x * blockDim.x + threadIdx.x;  // Q_ELEMS/4 threads
    const int g   = tid << 2;
    const int bq  = g >> 20;
    const int c   = (g >> 12) & 255;
    const int hw  = g & 4095;
    const int n   = (bq << 12) | hw;

    const int4   id4 = *(const int4*)(idx + n);
    const float4 xv  = *(const float4*)(x + g);
    float4 q;
    q.x = embed[id4.x * DIM + c];
    q.y = embed[id4.y * DIM + c];
    q.z = embed[id4.z * DIM + c];
    q.w = embed[id4.w * DIM + c];
    float4 d;
    d.x = q.x - xv.x; d.y = q.y - xv.y; d.z = q.z - xv.z; d.w = q.w - xv.w;
    float4 st;
    st.x = xv.x + d.x; st.y = xv.y + d.y; st.z = xv.z + d.z; st.w = xv.w + d.w;
    *(float4*)(out + g) = st;

    float ls = d.x * d.x + d.y * d.y + d.z * d.z + d.w * d.w;
    #pragma unroll
    for (int o = 32; o > 0; o >>= 1) ls += __shfl_down(ls, o, 64);
    __shared__ float ps[4];
    if ((threadIdx.x & 63) == 0) ps[threadIdx.x >> 6] = ls;
    __syncthreads();
    if (threadIdx.x == 0) atomicAdd(loss_accum, ps[0] + ps[1] + ps[2] + ps[3]);

    // indices as float, appended after quantized output
    if (tid < N_ROWS / 4) {
        const int4 iv = *(const int4*)(idx + (tid << 2));
        float4 f;
        f.x = (float)iv.x; f.y = (float)iv.y; f.z = (float)iv.z; f.w = (float)iv.w;
        *(float4*)(out + Q_ELEMS + (tid << 2)) = f;
    }
}

__global__ void finalize_loss(const float* __restrict__ loss_accum, float* __restrict__ out) {
    out[Q_ELEMS + N_ROWS] = COMMIT_COST * (*loss_accum) / (float)Q_ELEMS;
}

// ---------------------------------------------------------------------------
extern "C" void kernel_launch(void* const* d_in, const int* in_sizes, int n_in,
                              void* d_out, int out_size, void* d_ws, size_t ws_size,
                              hipStream_t stream) {
    const float* x     = (const float*)d_in[0];   // [16,256,64,64]
    const float* embed = (const float*)d_in[1];   // [1024,256]
    float* ws    = (float*)d_ws;
    float* Bc    = ws + WS_BC;
    float* bias  = ws + WS_BIAS;
    int*   idx   = (int*)(ws + WS_IDX);
    float* lacc  = ws + WS_LOSS;
    float* out   = (float*)d_out;

    hipLaunchKernelGGL(prep_embed, dim3(KCB), dim3(DIM), 0, stream, embed, Bc, bias, lacc);
    hipLaunchKernelGGL(dist_argmin, dim3(N_ROWS / MT), dim3(256), 0, stream, x, Bc, bias, idx);
    hipLaunchKernelGGL(gather_out, dim3(Q_ELEMS / 4 / 256), dim3(256), 0, stream, x, embed, idx, out, lacc);
    hipLaunchKernelGGL(finalize_loss, dim3(1), dim3(1), 0, stream, lacc, out);
}

// Round 3
// 659.243 us; speedup vs baseline: 2.3539x; 2.3539x over previous
//
#include <hip/hip_runtime.h>
#include <stdint.h>

#define DIM 256
#define HWSZ 4096
#define N_ROWS 65536
#define KCB 1024
#define Q_ELEMS 16777216
#define COMMIT 0.25f

typedef __attribute__((ext_vector_type(8))) _Float16 f16x8;
typedef __attribute__((ext_vector_type(4))) float f32x4;

// ws byte offsets
#define OFF_BH   0u           // fp16 [1024 cols][768 k] (granule-swizzled)
#define OFF_BL   1572864u     // fp16 [1024 cols][768 k] (granule-swizzled)
#define OFF_BIAS 3145728u     // f32 [1024]
#define OFF_CVAL 3149824u     // f32 [16 slots][65536]
#define OFF_CIDX 7344128u     // i32 [16 slots][65536]
#define OFF_IDX  11538432u    // i32 [65536]
#define OFF_LOSS 11800576u    // f32 [1]

#define MFMA(a, b, c) __builtin_amdgcn_mfma_f32_16x16x32_f16(a, b, c, 0, 0, 0)

__device__ __forceinline__ void splitf16(float p, unsigned& hbits, unsigned& lbits) {
    // round-to-nearest fp16 split: p = h + l, residual <= 2^-24 |p|
    const _Float16 h = (_Float16)p;
    const float hf = (float)h;
    const _Float16 l = (_Float16)(p - hf);
    hbits = (unsigned)__builtin_bit_cast(unsigned short, h);
    lbits = (unsigned)__builtin_bit_cast(unsigned short, l);
}

__device__ __forceinline__ void glds16(const unsigned short* src, unsigned short* dst) {
    __builtin_amdgcn_global_load_lds((const __attribute__((address_space(1))) void*)src,
                                     (__attribute__((address_space(3))) void*)dst, 16, 0, 0);
}

// ---------------------------------------------------------------------------
// B = [-4e^3; 6e^2; -4e] as fp16 hi/lo, layout [col][k] with 16B granules
// pre-permuted so a linear global_load_lds lands XOR-swizzled in LDS
// (reader applies granule ^= (col>>1)&3).
__global__ void prep_embed(const float* __restrict__ embed,
                           unsigned short* __restrict__ Bh, unsigned short* __restrict__ Bl,
                           float* __restrict__ bias, float* __restrict__ loss) {
    const int col = blockIdx.x, c = threadIdx.x;
    const float e = embed[col * DIM + c];
    const float e2 = e * e, e3 = e2 * e, e4 = e2 * e2;
    const float wv[3] = {-4.f * e3, 6.f * e2, -4.f * e};
    const int g = (c >> 3) & 3, j = c & 7, kb = c & 0xE0;
    const int swz = (col >> 1) & 3;
    #pragma unroll
    for (int s = 0; s < 3; ++s) {
        unsigned hb, lb;
        splitf16(wv[s], hb, lb);
        const int pos = col * 768 + s * 256 + kb + ((g ^ swz) << 3) + j;
        Bh[pos] = (unsigned short)hb;
        Bl[pos] = (unsigned short)lb;
    }
    __shared__ float red[256];
    red[c] = e4;
    __syncthreads();
    for (int o = 128; o > 0; o >>= 1) { if (c < o) red[c] += red[c + o]; __syncthreads(); }
    if (c == 0) { bias[col] = red[0]; if (col == 0) *loss = 0.f; }
}

// ---------------------------------------------------------------------------
// MFMA distance GEMM (3-term fp16 split ~ fp32 accuracy) + per-block argmin.
__launch_bounds__(256, 2)
__global__ void dist_mfma(const float* __restrict__ x,
                          const unsigned short* __restrict__ Bh,
                          const unsigned short* __restrict__ Bl,
                          const float* __restrict__ bias,
                          float* __restrict__ cval, int* __restrict__ cidx) {
    __shared__ __align__(16) unsigned char smem[32768];
    char* As_h = (char*)smem;            // [128 m][32 k] fp16, XOR-swizzled granules
    char* As_l = (char*)smem + 8192;
    char* Bs_h = (char*)smem + 16384;    // [128 col][32 k] fp16, XOR-swizzled granules
    char* Bs_l = (char*)smem + 24576;

    const int t = threadIdx.x;
    const int rowblk = blockIdx.x >> 3, colblk = blockIdx.x & 7;
    const int n0 = rowblk << 7;
    const float* xb = x + (((size_t)(n0 >> 12)) << 20) + (n0 & 4095);

    const int w = t >> 6, l = t & 63;
    const int lr = l & 15, lg = l >> 4;
    const int wrow = (w >> 1) << 6, wcol = (w & 1) << 6;

    // LDS fragment read byte-offsets (constant over kk)
    int aoff[4], boff[4];
    #pragma unroll
    for (int mi = 0; mi < 4; ++mi) {
        const int row = wrow + mi * 16 + lr;
        aoff[mi] = row * 64 + ((lg ^ ((row >> 1) & 3)) << 4);
    }
    #pragma unroll
    for (int ni = 0; ni < 4; ++ni) {
        const int cl = wcol + ni * 16 + lr;
        boff[ni] = cl * 64 + ((lg ^ ((cl >> 1) & 3)) << 4);
    }

    // A staging: thread -> row sm, channel group cg (16 ch each)
    const int sm = t & 127, cg = t >> 7;
    const int aswz = (sm >> 1) & 3;
    const int wo0 = (sm << 6) + (((cg * 2 + 0) ^ aswz) << 4);
    const int wo1 = (sm << 6) + (((cg * 2 + 1) ^ aswz) << 4);

    // B staging via global_load_lds (16B/lane, linear dest; source pre-swizzled)
    const int bcol = t >> 2, bk16 = t & 3;
    const size_t bgbase = (size_t)(colblk * 128 + bcol) * 768 + bk16 * 8;
    unsigned short* ldsBh0 = (unsigned short*)Bs_h + t * 8;
    unsigned short* ldsBh1 = (unsigned short*)Bs_h + 2048 + t * 8;
    unsigned short* ldsBl0 = (unsigned short*)Bs_l + t * 8;
    unsigned short* ldsBl1 = (unsigned short*)Bs_l + 2048 + t * 8;

    f32x4 acc[4][4];
    #pragma unroll
    for (int mi = 0; mi < 4; ++mi)
        #pragma unroll
        for (int ni = 0; ni < 4; ++ni) acc[mi][ni] = (f32x4){0.f, 0.f, 0.f, 0.f};

    #pragma unroll 1
    for (int kk = 0; kk < 24; ++kk) {
        const int cc = kk / 3;              // channel chunk (x re-read is L1/L2-hot)
        const int s  = kk - cc * 3;         // power section
        const int kgl = s * 256 + cc * 32;  // global k base

        glds16(Bh + bgbase + kgl, ldsBh0);
        glds16(Bh + bgbase + (size_t)64 * 768 + kgl, ldsBh1);
        glds16(Bl + bgbase + kgl, ldsBl0);
        glds16(Bl + bgbase + (size_t)64 * 768 + kgl, ldsBl1);

        const float* xc = xb + (((size_t)(cc * 32 + cg * 16)) << 12) + sm;
        #pragma unroll
        for (int half = 0; half < 2; ++half) {
            unsigned hw_[4], lw_[4];
            #pragma unroll
            for (int jp = 0; jp < 4; ++jp) {
                const float v0 = xc[(size_t)(half * 8 + jp * 2) << 12];
                const float v1 = xc[(size_t)(half * 8 + jp * 2 + 1) << 12];
                float p0 = v0, p1 = v1;
                if (s >= 1) { p0 *= v0; p1 *= v1; }
                if (s == 2) { p0 *= v0; p1 *= v1; }
                unsigned h0, l0, h1, l1;
                splitf16(p0, h0, l0);
                splitf16(p1, h1, l1);
                hw_[jp] = h0 | (h1 << 16);
                lw_[jp] = l0 | (l1 << 16);
            }
            const int wo = half ? wo1 : wo0;
            *(uint4*)(As_h + wo) = make_uint4(hw_[0], hw_[1], hw_[2], hw_[3]);
            *(uint4*)(As_l + wo) = make_uint4(lw_[0], lw_[1], lw_[2], lw_[3]);
        }
        __syncthreads();

        f16x8 vbh[4], vbl[4];
        #pragma unroll
        for (int ni = 0; ni < 4; ++ni) {
            vbh[ni] = *(const f16x8*)(Bs_h + boff[ni]);
            vbl[ni] = *(const f16x8*)(Bs_l + boff[ni]);
        }
        #pragma unroll
        for (int mi = 0; mi < 4; ++mi) {
            const f16x8 ah = *(const f16x8*)(As_h + aoff[mi]);
            const f16x8 al = *(const f16x8*)(As_l + aoff[mi]);
            #pragma unroll
            for (int ni = 0; ni < 4; ++ni) {
                acc[mi][ni] = MFMA(ah, vbh[ni], acc[mi][ni]);
                acc[mi][ni] = MFMA(al, vbh[ni], acc[mi][ni]);
                acc[mi][ni] = MFMA(ah, vbl[ni], acc[mi][ni]);
            }
        }
        __syncthreads();
    }

    // ---- epilogue: bias add + local argmin (C/D: col=lane&15, row=(lane>>4)*4+reg)
    const int colbase = colblk * 128 + wcol;
    float bs[4];
    #pragma unroll
    for (int ni = 0; ni < 4; ++ni) bs[ni] = bias[colbase + ni * 16 + lr];
    const int slot = colblk * 2 + (w & 1);
    #pragma unroll
    for (int mi = 0; mi < 4; ++mi) {
        #pragma unroll
        for (int r = 0; r < 4; ++r) {
            float bv = acc[mi][0][r] + bs[0];
            int bi = colbase + lr;
            #pragma unroll
            for (int ni = 1; ni < 4; ++ni) {
                const float v2 = acc[mi][ni][r] + bs[ni];
                if (v2 < bv) { bv = v2; bi = colbase + ni * 16 + lr; }
            }
            #pragma unroll
            for (int o = 1; o < 16; o <<= 1) {
                const float ov = __shfl_xor(bv, o, 64);
                const int oi = __shfl_xor(bi, o, 64);
                if (ov < bv || (ov == bv && oi < bi)) { bv = ov; bi = oi; }
            }
            if (lr == 0) {
                const int n = n0 + wrow + mi * 16 + lg * 4 + r;
                cval[slot * N_ROWS + n] = bv;
                cidx[slot * N_ROWS + n] = bi;
            }
        }
    }
}

// ---------------------------------------------------------------------------
__global__ void reduce_argmin(const float* __restrict__ cval, const int* __restrict__ cidx,
                              int* __restrict__ idx) {
    const int n = blockIdx.x * 256 + threadIdx.x;
    float bv = cval[n];
    int bi = cidx[n];
    #pragma unroll
    for (int s = 1; s < 16; ++s) {
        const float v = cval[s * N_ROWS + n];
        const int i = cidx[s * N_ROWS + n];
        if (v < bv || (v == bv && i < bi)) { bv = v; bi = i; }
    }
    idx[n] = bi;
}

// ---------------------------------------------------------------------------
__global__ void gather_out(const float* __restrict__ x, const float* __restrict__ embed,
                           const int* __restrict__ idx, float* __restrict__ out,
                           float* __restrict__ loss_accum) {
    const int tid = blockIdx.x * blockDim.x + threadIdx.x;
    const int g = tid << 2;
    const int bq = g >> 20;
    const int c = (g >> 12) & 255;
    const int hw = g & 4095;
    const int n = (bq << 12) | hw;

    const int4 id4 = *(const int4*)(idx + n);
    const float4 xv = *(const float4*)(x + g);
    float4 q;
    q.x = embed[id4.x * DIM + c];
    q.y = embed[id4.y * DIM + c];
    q.z = embed[id4.z * DIM + c];
    q.w = embed[id4.w * DIM + c];
    float4 d;
    d.x = q.x - xv.x; d.y = q.y - xv.y; d.z = q.z - xv.z; d.w = q.w - xv.w;
    float4 st;
    st.x = xv.x + d.x; st.y = xv.y + d.y; st.z = xv.z + d.z; st.w = xv.w + d.w;
    *(float4*)(out + g) = st;

    float ls = d.x * d.x + d.y * d.y + d.z * d.z + d.w * d.w;
    #pragma unroll
    for (int o = 32; o > 0; o >>= 1) ls += __shfl_down(ls, o, 64);
    __shared__ float ps[4];
    if ((threadIdx.x & 63) == 0) ps[threadIdx.x >> 6] = ls;
    __syncthreads();
    if (threadIdx.x == 0) atomicAdd(loss_accum, ps[0] + ps[1] + ps[2] + ps[3]);

    if (tid < N_ROWS / 4) {
        const int4 iv = *(const int4*)(idx + (tid << 2));
        float4 f;
        f.x = (float)iv.x; f.y = (float)iv.y; f.z = (float)iv.z; f.w = (float)iv.w;
        *(float4*)(out + Q_ELEMS + (tid << 2)) = f;
    }
}

__global__ void finalize_loss(const float* __restrict__ loss_accum, float* __restrict__ out) {
    out[Q_ELEMS + N_ROWS] = COMMIT * (*loss_accum) / (float)Q_ELEMS;
}

// ---------------------------------------------------------------------------
extern "C" void kernel_launch(void* const* d_in, const int* in_sizes, int n_in,
                              void* d_out, int out_size, void* d_ws, size_t ws_size,
                              hipStream_t stream) {
    const float* x = (const float*)d_in[0];
    const float* embed = (const float*)d_in[1];
    char* ws = (char*)d_ws;
    unsigned short* Bh = (unsigned short*)(ws + OFF_BH);
    unsigned short* Bl = (unsigned short*)(ws + OFF_BL);
    float* bias = (float*)(ws + OFF_BIAS);
    float* cval = (float*)(ws + OFF_CVAL);
    int* cidx = (int*)(ws + OFF_CIDX);
    int* idx = (int*)(ws + OFF_IDX);
    float* lacc = (float*)(ws + OFF_LOSS);
    float* out = (float*)d_out;

    hipLaunchKernelGGL(prep_embed, dim3(KCB), dim3(DIM), 0, stream, embed, Bh, Bl, bias, lacc);
    hipLaunchKernelGGL(dist_mfma, dim3(4096), dim3(256), 0, stream, x, Bh, Bl, bias, cval, cidx);
    hipLaunchKernelGGL(reduce_argmin, dim3(N_ROWS / 256), dim3(256), 0, stream, cval, cidx, idx);
    hipLaunchKernelGGL(gather_out, dim3(Q_ELEMS / 4 / 256), dim3(256), 0, stream, x, embed, idx, out, lacc);
    hipLaunchKernelGGL(finalize_loss, dim3(1), dim3(1), 0, stream, lacc, out);
}

// Round 5
// 572.174 us; speedup vs baseline: 2.7121x; 1.1522x over previous
//
#include <hip/hip_runtime.h>
#include <stdint.h>

#define DIM 256
#define HWSZ 4096
#define N_ROWS 65536
#define KCB 1024
#define Q_ELEMS 16777216
#define COMMIT 0.25f
#define PASS_ROWS 16384

typedef __attribute__((ext_vector_type(8))) _Float16 f16x8;
typedef __attribute__((ext_vector_type(4))) float f32x4;

// ws byte offsets
#define OFF_BH   0u           // fp16 [1024 cols][768 k] (granule-swizzled)
#define OFF_BL   1572864u
#define OFF_BIAS 3145728u     // f32 [1024]
#define OFF_CVAL 3149824u     // f32 [16 slots][65536]
#define OFF_CIDX 7344128u     // i32 [16 slots][65536]
#define OFF_IDX  11538432u    // i32 [65536]
#define OFF_LOSS 11800576u    // f32 [1]
#define OFF_AH   11800832u    // fp16 [128 rowblk][24 kk][128 row][32 k] per pass
#define OFF_AL   36966656u
#define WS_NEED  62132480ull

#define MFMA(a, b, c) __builtin_amdgcn_mfma_f32_16x16x32_f16(a, b, c, 0, 0, 0)

__device__ __forceinline__ void splitf16(float p, unsigned& hbits, unsigned& lbits) {
    const _Float16 h = (_Float16)p;
    const float hf = (float)h;
    const _Float16 l = (_Float16)(p - hf);
    hbits = (unsigned)__builtin_bit_cast(unsigned short, h);
    lbits = (unsigned)__builtin_bit_cast(unsigned short, l);
}

__device__ __forceinline__ void glds16(const unsigned short* src, unsigned short* dst) {
    __builtin_amdgcn_global_load_lds((const __attribute__((address_space(1))) void*)src,
                                     (__attribute__((address_space(3))) void*)dst, 16, 0, 0);
}

// ---------------------------------------------------------------------------
// B = [-4e^3; 6e^2; -4e] fp16 hi/lo, [col][768k], 16B granules pre-permuted
// (reader XORs granule with (col>>1)&3). Verbatim from round 3 (proven).
__global__ void prep_embed(const float* __restrict__ embed,
                           unsigned short* __restrict__ Bh, unsigned short* __restrict__ Bl,
                           float* __restrict__ bias, float* __restrict__ loss) {
    const int col = blockIdx.x, c = threadIdx.x;
    const float e = embed[col * DIM + c];
    const float e2 = e * e, e3 = e2 * e, e4 = e2 * e2;
    const float wv[3] = {-4.f * e3, 6.f * e2, -4.f * e};
    const int g = (c >> 3) & 3, j = c & 7, kb = c & 0xE0;
    const int swz = (col >> 1) & 3;
    #pragma unroll
    for (int s = 0; s < 3; ++s) {
        unsigned hb, lb;
        splitf16(wv[s], hb, lb);
        const int pos = col * 768 + s * 256 + kb + ((g ^ swz) << 3) + j;
        Bh[pos] = (unsigned short)hb;
        Bl[pos] = (unsigned short)lb;
    }
    __shared__ float red[256];
    red[c] = e4;
    __syncthreads();
    for (int o = 128; o > 0; o >>= 1) { if (c < o) red[c] += red[c + o]; __syncthreads(); }
    if (c == 0) { bias[col] = red[0]; if (col == 0) *loss = 0.f; }
}

// ---------------------------------------------------------------------------
// Materialize split-fp16 A tiles for one pass of 16384 rows.
// Layout: Ah[((rowblk*24 + kk)*128 + rit)*32 + granule-permuted] — exactly the
// LDS image dist_mfma wants, so its global_load_lds is linear.
__global__ void convert_x(const float* __restrict__ x, int passBase,
                          unsigned short* __restrict__ Ah, unsigned short* __restrict__ Al) {
    const int t = threadIdx.x;
    const int sm = t & 63, q = t >> 6;
    const int b = blockIdx.x;
    const int n = passBase + b * 64 + sm;            // global row
    const int rit = ((b & 1) << 6) + sm;             // row within 128-tile
    const int rbl = b >> 1;                           // rowblk within pass
    const float* xp = x + (((size_t)(n >> 12)) << 20) + (n & 4095);
    const int swz = (rit >> 1) & 3;

    #pragma unroll
    for (int h2 = 0; h2 < 2; ++h2) {
        const int cc = q * 2 + h2;
        float xv[32], pw[32];
        #pragma unroll
        for (int j = 0; j < 32; ++j) {
            xv[j] = xp[(size_t)(cc * 32 + j) << 12];
            pw[j] = xv[j];
        }
        #pragma unroll
        for (int s = 0; s < 3; ++s) {
            if (s) {
                #pragma unroll
                for (int j = 0; j < 32; ++j) pw[j] *= xv[j];
            }
            const int kk = cc * 3 + s;
            const size_t base = (((size_t)(rbl * 24 + kk)) * 128 + rit) * 32;
            #pragma unroll
            for (int g = 0; g < 4; ++g) {
                unsigned hw_[4], lw_[4];
                #pragma unroll
                for (int e = 0; e < 4; ++e) {
                    unsigned h0, l0, h1, l1;
                    splitf16(pw[g * 8 + 2 * e], h0, l0);
                    splitf16(pw[g * 8 + 2 * e + 1], h1, l1);
                    hw_[e] = h0 | (h1 << 16);
                    lw_[e] = l0 | (l1 << 16);
                }
                const int go = (g ^ swz) << 3;
                *(uint4*)(Ah + base + go) = make_uint4(hw_[0], hw_[1], hw_[2], hw_[3]);
                *(uint4*)(Al + base + go) = make_uint4(lw_[0], lw_[1], lw_[2], lw_[3]);
            }
        }
    }
}

// ---------------------------------------------------------------------------
// Pure-MFMA distance GEMM: both operands via global_load_lds, double-buffered,
// ONE barrier per k-step (prefetch kk+1 flies under MFMA kk). Round-3 geometry:
// 256 threads, 4 waves, MT=128, NT=128, acc[4][4]; round-3 fragment formulas.
__launch_bounds__(256, 2)
__global__ void dist_mfma(const unsigned short* __restrict__ Ah,
                          const unsigned short* __restrict__ Al,
                          const unsigned short* __restrict__ Bh,
                          const unsigned short* __restrict__ Bl,
                          const float* __restrict__ bias, int passBase,
                          float* __restrict__ cval, int* __restrict__ cidx) {
    __shared__ __align__(16) unsigned char smem[65536];
    // per 32KB buffer (shorts): As_h 0..4095, As_l 4096..8191,
    //                           Bs_h 8192..12287, Bs_l 12288..16383

    const int t = threadIdx.x;
    const int rbl = blockIdx.x >> 3, colblk = blockIdx.x & 7;
    const int n0 = passBase + (rbl << 7);

    const int w = t >> 6, l = t & 63;
    const int lr = l & 15, lg = l >> 4;
    const int wrow = (w >> 1) << 6, wcol = (w & 1) << 6;

    int aoff[4], boff[4];
    #pragma unroll
    for (int mi = 0; mi < 4; ++mi) {
        const int row = wrow + mi * 16 + lr;
        aoff[mi] = row * 64 + ((lg ^ ((row >> 1) & 3)) << 4);
    }
    #pragma unroll
    for (int ni = 0; ni < 4; ++ni) {
        const int cl = wcol + ni * 16 + lr;
        boff[ni] = 16384 + cl * 64 + ((lg ^ ((cl >> 1) & 3)) << 4);
    }

    const int bcol = t >> 2;
    const size_t bsrc0 = (size_t)(colblk * 128 + bcol) * 768 + (t & 3) * 8;
    const size_t bsrc1 = bsrc0 + (size_t)64 * 768;
    const size_t atileBase = (size_t)rbl * 24 * 4096;   // shorts

    auto stage = [&](int kk, int buf) {
        const int cc = kk / 3, s = kk - cc * 3;
        const int kgl = s * 256 + cc * 32;
        unsigned short* base = (unsigned short*)(smem + (buf << 15));
        const unsigned short* ah = Ah + atileBase + (size_t)kk * 4096;
        const unsigned short* al = Al + atileBase + (size_t)kk * 4096;
        glds16(ah + t * 8, base + t * 8);
        glds16(ah + 2048 + t * 8, base + 2048 + t * 8);
        glds16(al + t * 8, base + 4096 + t * 8);
        glds16(al + 2048 + t * 8, base + 4096 + 2048 + t * 8);
        glds16(Bh + bsrc0 + kgl, base + 8192 + t * 8);
        glds16(Bh + bsrc1 + kgl, base + 8192 + 2048 + t * 8);
        glds16(Bl + bsrc0 + kgl, base + 12288 + t * 8);
        glds16(Bl + bsrc1 + kgl, base + 12288 + 2048 + t * 8);
    };

    f32x4 acc[4][4];
    #pragma unroll
    for (int mi = 0; mi < 4; ++mi)
        #pragma unroll
        for (int ni = 0; ni < 4; ++ni) acc[mi][ni] = (f32x4){0.f, 0.f, 0.f, 0.f};

    stage(0, 0);
    #pragma unroll 1
    for (int kk = 0; kk < 24; ++kk) {
        __syncthreads();   // vmcnt drain: buf[kk&1] ready; prior reads of other buf done
        if (kk < 23) stage(kk + 1, (kk + 1) & 1);
        const int bofs = (kk & 1) << 15;

        f16x8 vbh[4], vbl[4];
        #pragma unroll
        for (int ni = 0; ni < 4; ++ni) {
            vbh[ni] = *(const f16x8*)(smem + bofs + boff[ni]);
            vbl[ni] = *(const f16x8*)(smem + bofs + boff[ni] + 8192);
        }
        #pragma unroll
        for (int mi = 0; mi < 4; ++mi) {
            const f16x8 ah = *(const f16x8*)(smem + bofs + aoff[mi]);
            const f16x8 al = *(const f16x8*)(smem + bofs + aoff[mi] + 8192);
            #pragma unroll
            for (int ni = 0; ni < 4; ++ni) {
                acc[mi][ni] = MFMA(ah, vbh[ni], acc[mi][ni]);
                acc[mi][ni] = MFMA(al, vbh[ni], acc[mi][ni]);
                acc[mi][ni] = MFMA(ah, vbl[ni], acc[mi][ni]);
            }
        }
    }

    // epilogue (verbatim round 3): C/D col=lane&15, row=(lane>>4)*4+reg
    const int colbase = colblk * 128 + wcol;
    float bs[4];
    #pragma unroll
    for (int ni = 0; ni < 4; ++ni) bs[ni] = bias[colbase + ni * 16 + lr];
    const int slot = colblk * 2 + (w & 1);
    #pragma unroll
    for (int mi = 0; mi < 4; ++mi) {
        #pragma unroll
        for (int r = 0; r < 4; ++r) {
            float bv = acc[mi][0][r] + bs[0];
            int bi = colbase + lr;
            #pragma unroll
            for (int ni = 1; ni < 4; ++ni) {
                const float v2 = acc[mi][ni][r] + bs[ni];
                if (v2 < bv) { bv = v2; bi = colbase + ni * 16 + lr; }
            }
            #pragma unroll
            for (int o = 1; o < 16; o <<= 1) {
                const float ov = __shfl_xor(bv, o, 64);
                const int oi = __shfl_xor(bi, o, 64);
                if (ov < bv || (ov == bv && oi < bi)) { bv = ov; bi = oi; }
            }
            if (lr == 0) {
                const int n = n0 + wrow + mi * 16 + lg * 4 + r;
                cval[slot * N_ROWS + n] = bv;
                cidx[slot * N_ROWS + n] = bi;
            }
        }
    }
}

// ---------------------------------------------------------------------------
// Fallback (ws too small): verbatim round-3 kernel (proven, 385 us).
__launch_bounds__(256, 2)
__global__ void dist_mfma_fb(const float* __restrict__ x,
                             const unsigned short* __restrict__ Bh,
                             const unsigned short* __restrict__ Bl,
                             const float* __restrict__ bias,
                             float* __restrict__ cval, int* __restrict__ cidx) {
    __shared__ __align__(16) unsigned char smem[32768];
    char* As_h = (char*)smem;
    char* As_l = (char*)smem + 8192;
    char* Bs_h = (char*)smem + 16384;
    char* Bs_l = (char*)smem + 24576;

    const int t = threadIdx.x;
    const int rowblk = blockIdx.x >> 3, colblk = blockIdx.x & 7;
    const int n0 = rowblk << 7;
    const float* xb = x + (((size_t)(n0 >> 12)) << 20) + (n0 & 4095);

    const int w = t >> 6, l = t & 63;
    const int lr = l & 15, lg = l >> 4;
    const int wrow = (w >> 1) << 6, wcol = (w & 1) << 6;

    int aoff[4], boff[4];
    #pragma unroll
    for (int mi = 0; mi < 4; ++mi) {
        const int row = wrow + mi * 16 + lr;
        aoff[mi] = row * 64 + ((lg ^ ((row >> 1) & 3)) << 4);
    }
    #pragma unroll
    for (int ni = 0; ni < 4; ++ni) {
        const int cl = wcol + ni * 16 + lr;
        boff[ni] = cl * 64 + ((lg ^ ((cl >> 1) & 3)) << 4);
    }

    const int sm = t & 127, cg = t >> 7;
    const int aswz = (sm >> 1) & 3;
    const int wo0 = (sm << 6) + (((cg * 2 + 0) ^ aswz) << 4);
    const int wo1 = (sm << 6) + (((cg * 2 + 1) ^ aswz) << 4);

    const int bcol = t >> 2;
    const size_t bgbase = (size_t)(colblk * 128 + bcol) * 768 + (t & 3) * 8;
    unsigned short* ldsBh0 = (unsigned short*)Bs_h + t * 8;
    unsigned short* ldsBh1 = (unsigned short*)Bs_h + 2048 + t * 8;
    unsigned short* ldsBl0 = (unsigned short*)Bs_l + t * 8;
    unsigned short* ldsBl1 = (unsigned short*)Bs_l + 2048 + t * 8;

    f32x4 acc[4][4];
    #pragma unroll
    for (int mi = 0; mi < 4; ++mi)
        #pragma unroll
        for (int ni = 0; ni < 4; ++ni) acc[mi][ni] = (f32x4){0.f, 0.f, 0.f, 0.f};

    #pragma unroll 1
    for (int kk = 0; kk < 24; ++kk) {
        const int cc = kk / 3;
        const int s = kk - cc * 3;
        const int kgl = s * 256 + cc * 32;

        glds16(Bh + bgbase + kgl, ldsBh0);
        glds16(Bh + bgbase + (size_t)64 * 768 + kgl, ldsBh1);
        glds16(Bl + bgbase + kgl, ldsBl0);
        glds16(Bl + bgbase + (size_t)64 * 768 + kgl, ldsBl1);

        const float* xc = xb + (((size_t)(cc * 32 + cg * 16)) << 12) + sm;
        #pragma unroll
        for (int half = 0; half < 2; ++half) {
            unsigned hw_[4], lw_[4];
            #pragma unroll
            for (int jp = 0; jp < 4; ++jp) {
                const float v0 = xc[(size_t)(half * 8 + jp * 2) << 12];
                const float v1 = xc[(size_t)(half * 8 + jp * 2 + 1) << 12];
                float p0 = v0, p1 = v1;
                if (s >= 1) { p0 *= v0; p1 *= v1; }
                if (s == 2) { p0 *= v0; p1 *= v1; }
                unsigned h0, l0, h1, l1;
                splitf16(p0, h0, l0);
                splitf16(p1, h1, l1);
                hw_[jp] = h0 | (h1 << 16);
                lw_[jp] = l0 | (l1 << 16);
            }
            const int wo = half ? wo1 : wo0;
            *(uint4*)(As_h + wo) = make_uint4(hw_[0], hw_[1], hw_[2], hw_[3]);
            *(uint4*)(As_l + wo) = make_uint4(lw_[0], lw_[1], lw_[2], lw_[3]);
        }
        __syncthreads();

        f16x8 vbh[4], vbl[4];
        #pragma unroll
        for (int ni = 0; ni < 4; ++ni) {
            vbh[ni] = *(const f16x8*)(Bs_h + boff[ni]);
            vbl[ni] = *(const f16x8*)(Bs_l + boff[ni]);
        }
        #pragma unroll
        for (int mi = 0; mi < 4; ++mi) {
            const f16x8 ah = *(const f16x8*)(As_h + aoff[mi]);
            const f16x8 al = *(const f16x8*)(As_l + aoff[mi]);
            #pragma unroll
            for (int ni = 0; ni < 4; ++ni) {
                acc[mi][ni] = MFMA(ah, vbh[ni], acc[mi][ni]);
                acc[mi][ni] = MFMA(al, vbh[ni], acc[mi][ni]);
                acc[mi][ni] = MFMA(ah, vbl[ni], acc[mi][ni]);
            }
        }
        __syncthreads();
    }

    const int colbase = colblk * 128 + wcol;
    float bs[4];
    #pragma unroll
    for (int ni = 0; ni < 4; ++ni) bs[ni] = bias[colbase + ni * 16 + lr];
    const int slot = colblk * 2 + (w & 1);
    #pragma unroll
    for (int mi = 0; mi < 4; ++mi) {
        #pragma unroll
        for (int r = 0; r < 4; ++r) {
            float bv = acc[mi][0][r] + bs[0];
            int bi = colbase + lr;
            #pragma unroll
            for (int ni = 1; ni < 4; ++ni) {
                const float v2 = acc[mi][ni][r] + bs[ni];
                if (v2 < bv) { bv = v2; bi = colbase + ni * 16 + lr; }
            }
            #pragma unroll
            for (int o = 1; o < 16; o <<= 1) {
                const float ov = __shfl_xor(bv, o, 64);
                const int oi = __shfl_xor(bi, o, 64);
                if (ov < bv || (ov == bv && oi < bi)) { bv = ov; bi = oi; }
            }
            if (lr == 0) {
                const int n = n0 + wrow + mi * 16 + lg * 4 + r;
                cval[slot * N_ROWS + n] = bv;
                cidx[slot * N_ROWS + n] = bi;
            }
        }
    }
}

// ---------------------------------------------------------------------------
__global__ void reduce_argmin(const float* __restrict__ cval, const int* __restrict__ cidx,
                              int* __restrict__ idx) {
    const int n = blockIdx.x * 256 + threadIdx.x;
    float bv = cval[n];
    int bi = cidx[n];
    #pragma unroll
    for (int s = 1; s < 16; ++s) {
        const float v = cval[s * N_ROWS + n];
        const int i = cidx[s * N_ROWS + n];
        if (v < bv || (v == bv && i < bi)) { bv = v; bi = i; }
    }
    idx[n] = bi;
}

// ---------------------------------------------------------------------------
__global__ void gather_out(const float* __restrict__ x, const float* __restrict__ embed,
                           const int* __restrict__ idx, float* __restrict__ out,
                           float* __restrict__ loss_accum) {
    const int gtid = blockIdx.x * 256 + threadIdx.x;
    float ls = 0.f;
    #pragma unroll
    for (int it = 0; it < 4; ++it) {
        const int tid = gtid + it * 1048576;
        const int g = tid << 2;
        const int bq = g >> 20;
        const int c = (g >> 12) & 255;
        const int hw = g & 4095;
        const int n = (bq << 12) | hw;

        const int4 id4 = *(const int4*)(idx + n);
        const float4 xv = *(const float4*)(x + g);
        float4 q;
        q.x = embed[id4.x * DIM + c];
        q.y = embed[id4.y * DIM + c];
        q.z = embed[id4.z * DIM + c];
        q.w = embed[id4.w * DIM + c];
        float4 d;
        d.x = q.x - xv.x; d.y = q.y - xv.y; d.z = q.z - xv.z; d.w = q.w - xv.w;
        float4 st;
        st.x = xv.x + d.x; st.y = xv.y + d.y; st.z = xv.z + d.z; st.w = xv.w + d.w;
        *(float4*)(out + g) = st;
        ls += d.x * d.x + d.y * d.y + d.z * d.z + d.w * d.w;
    }
    #pragma unroll
    for (int o = 32; o > 0; o >>= 1) ls += __shfl_down(ls, o, 64);
    __shared__ float ps[4];
    if ((threadIdx.x & 63) == 0) ps[threadIdx.x >> 6] = ls;
    __syncthreads();
    if (threadIdx.x == 0) atomicAdd(loss_accum, ps[0] + ps[1] + ps[2] + ps[3]);

    if (gtid < N_ROWS / 4) {
        const int4 iv = *(const int4*)(idx + (gtid << 2));
        float4 f;
        f.x = (float)iv.x; f.y = (float)iv.y; f.z = (float)iv.z; f.w = (float)iv.w;
        *(float4*)(out + Q_ELEMS + (gtid << 2)) = f;
    }
}

__global__ void finalize_loss(const float* __restrict__ loss_accum, float* __restrict__ out) {
    out[Q_ELEMS + N_ROWS] = COMMIT * (*loss_accum) / (float)Q_ELEMS;
}

// ---------------------------------------------------------------------------
extern "C" void kernel_launch(void* const* d_in, const int* in_sizes, int n_in,
                              void* d_out, int out_size, void* d_ws, size_t ws_size,
                              hipStream_t stream) {
    const float* x = (const float*)d_in[0];
    const float* embed = (const float*)d_in[1];
    char* ws = (char*)d_ws;
    unsigned short* Bh = (unsigned short*)(ws + OFF_BH);
    unsigned short* Bl = (unsigned short*)(ws + OFF_BL);
    float* bias = (float*)(ws + OFF_BIAS);
    float* cval = (float*)(ws + OFF_CVAL);
    int* cidx = (int*)(ws + OFF_CIDX);
    int* idx = (int*)(ws + OFF_IDX);
    float* lacc = (float*)(ws + OFF_LOSS);
    unsigned short* Ah = (unsigned short*)(ws + OFF_AH);
    unsigned short* Al = (unsigned short*)(ws + OFF_AL);
    float* out = (float*)d_out;

    hipLaunchKernelGGL(prep_embed, dim3(KCB), dim3(DIM), 0, stream, embed, Bh, Bl, bias, lacc);
    if (ws_size >= WS_NEED) {
        for (int p = 0; p < 4; ++p) {
            hipLaunchKernelGGL(convert_x, dim3(PASS_ROWS / 64), dim3(256), 0, stream,
                               x, p * PASS_ROWS, Ah, Al);
            hipLaunchKernelGGL(dist_mfma, dim3((PASS_ROWS / 128) * 8), dim3(256), 0, stream,
                               Ah, Al, Bh, Bl, bias, p * PASS_ROWS, cval, cidx);
        }
    } else {
        hipLaunchKernelGGL(dist_mfma_fb, dim3(4096), dim3(256), 0, stream,
                           x, Bh, Bl, bias, cval, cidx);
    }
    hipLaunchKernelGGL(reduce_argmin, dim3(N_ROWS / 256), dim3(256), 0, stream, cval, cidx, idx);
    hipLaunchKernelGGL(gather_out, dim3(4096), dim3(256), 0, stream, x, embed, idx, out, lacc);
    hipLaunchKernelGGL(finalize_loss, dim3(1), dim3(1), 0, stream, lacc, out);
}

// Round 6
// 555.621 us; speedup vs baseline: 2.7929x; 1.0298x over previous
//
#include <hip/hip_runtime.h>
#include <stdint.h>

#define DIM 256
#define HWSZ 4096
#define N_ROWS 65536
#define KCB 1024
#define Q_ELEMS 16777216
#define COMMIT 0.25f
#define PASS_ROWS 16384

typedef __attribute__((ext_vector_type(8))) _Float16 f16x8;
typedef __attribute__((ext_vector_type(4))) float f32x4;

// ws byte offsets
#define OFF_BH   0u           // fp16 [1024 cols][768 k] (granule-swizzled)
#define OFF_BL   1572864u
#define OFF_BIAS 3145728u     // f32 [1024]
#define OFF_CVAL 3149824u     // f32 [16 slots][65536]
#define OFF_CIDX 7344128u     // i32 [16 slots][65536]
#define OFF_IDX  11538432u    // i32 [65536]
#define OFF_LOSS 11800576u    // f32 [1]
#define OFF_AH   11800832u    // fp16 [128 rowblk][24 kk][128 row][32 k] per pass
#define OFF_AL   36966656u
#define WS_NEED  62132480ull

#define MFMA(a, b, c) __builtin_amdgcn_mfma_f32_16x16x32_f16(a, b, c, 0, 0, 0)

__device__ __forceinline__ void splitf16(float p, unsigned& hbits, unsigned& lbits) {
    const _Float16 h = (_Float16)p;
    const float hf = (float)h;
    const _Float16 l = (_Float16)(p - hf);
    hbits = (unsigned)__builtin_bit_cast(unsigned short, h);
    lbits = (unsigned)__builtin_bit_cast(unsigned short, l);
}

__device__ __forceinline__ void glds16(const unsigned short* src, unsigned short* dst) {
    __builtin_amdgcn_global_load_lds((const __attribute__((address_space(1))) void*)src,
                                     (__attribute__((address_space(3))) void*)dst, 16, 0, 0);
}

// ---------------------------------------------------------------------------
// B = [-4e^3; 6e^2; -4e] fp16 hi/lo, [col][768k], granule-swizzled. (proven)
__global__ void prep_embed(const float* __restrict__ embed,
                           unsigned short* __restrict__ Bh, unsigned short* __restrict__ Bl,
                           float* __restrict__ bias, float* __restrict__ loss) {
    const int col = blockIdx.x, c = threadIdx.x;
    const float e = embed[col * DIM + c];
    const float e2 = e * e, e3 = e2 * e, e4 = e2 * e2;
    const float wv[3] = {-4.f * e3, 6.f * e2, -4.f * e};
    const int g = (c >> 3) & 3, j = c & 7, kb = c & 0xE0;
    const int swz = (col >> 1) & 3;
    #pragma unroll
    for (int s = 0; s < 3; ++s) {
        unsigned hb, lb;
        splitf16(wv[s], hb, lb);
        const int pos = col * 768 + s * 256 + kb + ((g ^ swz) << 3) + j;
        Bh[pos] = (unsigned short)hb;
        Bl[pos] = (unsigned short)lb;
    }
    __shared__ float red[256];
    red[c] = e4;
    __syncthreads();
    for (int o = 128; o > 0; o >>= 1) { if (c < o) red[c] += red[c + o]; __syncthreads(); }
    if (c == 0) { bias[col] = red[0]; if (col == 0) *loss = 0.f; }
}

// ---------------------------------------------------------------------------
// Materialize split-fp16 A tiles for one pass of 16384 rows. (proven)
__global__ void convert_x(const float* __restrict__ x, int passBase,
                          unsigned short* __restrict__ Ah, unsigned short* __restrict__ Al) {
    const int t = threadIdx.x;
    const int sm = t & 63, q = t >> 6;
    const int b = blockIdx.x;
    const int n = passBase + b * 64 + sm;
    const int rit = ((b & 1) << 6) + sm;
    const int rbl = b >> 1;
    const float* xp = x + (((size_t)(n >> 12)) << 20) + (n & 4095);
    const int swz = (rit >> 1) & 3;

    #pragma unroll
    for (int h2 = 0; h2 < 2; ++h2) {
        const int cc = q * 2 + h2;
        float xv[32], pw[32];
        #pragma unroll
        for (int j = 0; j < 32; ++j) {
            xv[j] = xp[(size_t)(cc * 32 + j) << 12];
            pw[j] = xv[j];
        }
        #pragma unroll
        for (int s = 0; s < 3; ++s) {
            if (s) {
                #pragma unroll
                for (int j = 0; j < 32; ++j) pw[j] *= xv[j];
            }
            const int kk = cc * 3 + s;
            const size_t base = (((size_t)(rbl * 24 + kk)) * 128 + rit) * 32;
            #pragma unroll
            for (int g = 0; g < 4; ++g) {
                unsigned hw_[4], lw_[4];
                #pragma unroll
                for (int e = 0; e < 4; ++e) {
                    unsigned h0, l0, h1, l1;
                    splitf16(pw[g * 8 + 2 * e], h0, l0);
                    splitf16(pw[g * 8 + 2 * e + 1], h1, l1);
                    hw_[e] = h0 | (h1 << 16);
                    lw_[e] = l0 | (l1 << 16);
                }
                const int go = (g ^ swz) << 3;
                *(uint4*)(Ah + base + go) = make_uint4(hw_[0], hw_[1], hw_[2], hw_[3]);
                *(uint4*)(Al + base + go) = make_uint4(lw_[0], lw_[1], lw_[2], lw_[3]);
            }
        }
    }
}

// ---------------------------------------------------------------------------
// Pure-MFMA distance GEMM. Round-6 changes vs proven round-5:
//  (1) XCD-locality remap: the 8 colblocks of one rowblock land on ONE XCD
//      as consecutive slots -> A tile is 1x HBM + 7x L2.
//  (2) counted-vmcnt pipeline: stage(kk+1) issued first, then s_waitcnt
//      vmcnt(8) (stage(kk) complete; stage(kk+1) still in flight), s_barrier,
//      MFMA(kk), lgkmcnt(0)+s_barrier. No vmcnt(0) drain in the main loop.
__launch_bounds__(256, 2)
__global__ void dist_mfma(const unsigned short* __restrict__ Ah,
                          const unsigned short* __restrict__ Al,
                          const unsigned short* __restrict__ Bh,
                          const unsigned short* __restrict__ Bl,
                          const float* __restrict__ bias, int passBase,
                          float* __restrict__ cval, int* __restrict__ cidx) {
    __shared__ __align__(16) unsigned char smem[65536];
    // per 32KB buffer (shorts): As_h 0..4095, As_l 4096..8191,
    //                           Bs_h 8192..12287, Bs_l 12288..16383

    const int t = threadIdx.x;
    const int b = blockIdx.x;
    const int xcd = b & 7, slot = b >> 3;
    const int rbl = xcd + ((slot >> 3) << 3);   // same-rbl blocks: same XCD, consecutive slots
    const int colblk = slot & 7;
    const int n0 = passBase + (rbl << 7);

    const int w = t >> 6, l = t & 63;
    const int lr = l & 15, lg = l >> 4;
    const int wrow = (w >> 1) << 6, wcol = (w & 1) << 6;

    int aoff[4], boff[4];
    #pragma unroll
    for (int mi = 0; mi < 4; ++mi) {
        const int row = wrow + mi * 16 + lr;
        aoff[mi] = row * 64 + ((lg ^ ((row >> 1) & 3)) << 4);
    }
    #pragma unroll
    for (int ni = 0; ni < 4; ++ni) {
        const int cl = wcol + ni * 16 + lr;
        boff[ni] = 16384 + cl * 64 + ((lg ^ ((cl >> 1) & 3)) << 4);
    }

    const int bcol = t >> 2;
    const size_t bsrc0 = (size_t)(colblk * 128 + bcol) * 768 + (t & 3) * 8;
    const size_t bsrc1 = bsrc0 + (size_t)64 * 768;
    const size_t atileBase = (size_t)rbl * 24 * 4096;   // shorts

    auto stage = [&](int kk, int buf) {
        const int cc = kk / 3, s = kk - cc * 3;
        const int kgl = s * 256 + cc * 32;
        unsigned short* base = (unsigned short*)(smem + (buf << 15));
        const unsigned short* ah = Ah + atileBase + (size_t)kk * 4096;
        const unsigned short* al = Al + atileBase + (size_t)kk * 4096;
        glds16(ah + t * 8, base + t * 8);
        glds16(ah + 2048 + t * 8, base + 2048 + t * 8);
        glds16(al + t * 8, base + 4096 + t * 8);
        glds16(al + 2048 + t * 8, base + 4096 + 2048 + t * 8);
        glds16(Bh + bsrc0 + kgl, base + 8192 + t * 8);
        glds16(Bh + bsrc1 + kgl, base + 8192 + 2048 + t * 8);
        glds16(Bl + bsrc0 + kgl, base + 12288 + t * 8);
        glds16(Bl + bsrc1 + kgl, base + 12288 + 2048 + t * 8);
    };

    f32x4 acc[4][4];
    #pragma unroll
    for (int mi = 0; mi < 4; ++mi)
        #pragma unroll
        for (int ni = 0; ni < 4; ++ni) acc[mi][ni] = (f32x4){0.f, 0.f, 0.f, 0.f};

    stage(0, 0);
    #pragma unroll 1
    for (int kk = 0; kk < 24; ++kk) {
        // issue next tile's loads first (they fly across this iter's MFMA)
        if (kk < 23) {
            stage(kk + 1, (kk + 1) & 1);
            asm volatile("s_waitcnt vmcnt(8)" ::: "memory");   // stage(kk) complete
        } else {
            asm volatile("s_waitcnt vmcnt(0)" ::: "memory");
        }
        __builtin_amdgcn_sched_barrier(0);
        __builtin_amdgcn_s_barrier();          // all waves' stage(kk) parts landed
        __builtin_amdgcn_sched_barrier(0);

        const int bofs = (kk & 1) << 15;
        f16x8 vbh[4], vbl[4];
        #pragma unroll
        for (int ni = 0; ni < 4; ++ni) {
            vbh[ni] = *(const f16x8*)(smem + bofs + boff[ni]);
            vbl[ni] = *(const f16x8*)(smem + bofs + boff[ni] + 8192);
        }
        #pragma unroll
        for (int mi = 0; mi < 4; ++mi) {
            const f16x8 ah = *(const f16x8*)(smem + bofs + aoff[mi]);
            const f16x8 al = *(const f16x8*)(smem + bofs + aoff[mi] + 8192);
            #pragma unroll
            for (int ni = 0; ni < 4; ++ni) {
                acc[mi][ni] = MFMA(ah, vbh[ni], acc[mi][ni]);
                acc[mi][ni] = MFMA(al, vbh[ni], acc[mi][ni]);
                acc[mi][ni] = MFMA(ah, vbl[ni], acc[mi][ni]);
            }
        }
        asm volatile("s_waitcnt lgkmcnt(0)" ::: "memory");  // my ds_reads of buf[kk&1] done
        __builtin_amdgcn_sched_barrier(0);
        __builtin_amdgcn_s_barrier();          // nobody reads buf[kk&1] after this
        __builtin_amdgcn_sched_barrier(0);
    }

    // epilogue: C/D col=lane&15, row=(lane>>4)*4+reg  (proven)
    const int colbase = colblk * 128 + wcol;
    float bs[4];
    #pragma unroll
    for (int ni = 0; ni < 4; ++ni) bs[ni] = bias[colbase + ni * 16 + lr];
    const int slot2 = colblk * 2 + (w & 1);
    #pragma unroll
    for (int mi = 0; mi < 4; ++mi) {
        #pragma unroll
        for (int r = 0; r < 4; ++r) {
            float bv = acc[mi][0][r] + bs[0];
            int bi = colbase + lr;
            #pragma unroll
            for (int ni = 1; ni < 4; ++ni) {
                const float v2 = acc[mi][ni][r] + bs[ni];
                if (v2 < bv) { bv = v2; bi = colbase + ni * 16 + lr; }
            }
            #pragma unroll
            for (int o = 1; o < 16; o <<= 1) {
                const float ov = __shfl_xor(bv, o, 64);
                const int oi = __shfl_xor(bi, o, 64);
                if (ov < bv || (ov == bv && oi < bi)) { bv = ov; bi = oi; }
            }
            if (lr == 0) {
                const int n = n0 + wrow + mi * 16 + lg * 4 + r;
                cval[slot2 * N_ROWS + n] = bv;
                cidx[slot2 * N_ROWS + n] = bi;
            }
        }
    }
}

// ---------------------------------------------------------------------------
// Fallback (ws too small): verbatim round-3 kernel (proven).
__launch_bounds__(256, 2)
__global__ void dist_mfma_fb(const float* __restrict__ x,
                             const unsigned short* __restrict__ Bh,
                             const unsigned short* __restrict__ Bl,
                             const float* __restrict__ bias,
                             float* __restrict__ cval, int* __restrict__ cidx) {
    __shared__ __align__(16) unsigned char smem[32768];
    char* As_h = (char*)smem;
    char* As_l = (char*)smem + 8192;
    char* Bs_h = (char*)smem + 16384;
    char* Bs_l = (char*)smem + 24576;

    const int t = threadIdx.x;
    const int rowblk = blockIdx.x >> 3, colblk = blockIdx.x & 7;
    const int n0 = rowblk << 7;
    const float* xb = x + (((size_t)(n0 >> 12)) << 20) + (n0 & 4095);

    const int w = t >> 6, l = t & 63;
    const int lr = l & 15, lg = l >> 4;
    const int wrow = (w >> 1) << 6, wcol = (w & 1) << 6;

    int aoff[4], boff[4];
    #pragma unroll
    for (int mi = 0; mi < 4; ++mi) {
        const int row = wrow + mi * 16 + lr;
        aoff[mi] = row * 64 + ((lg ^ ((row >> 1) & 3)) << 4);
    }
    #pragma unroll
    for (int ni = 0; ni < 4; ++ni) {
        const int cl = wcol + ni * 16 + lr;
        boff[ni] = cl * 64 + ((lg ^ ((cl >> 1) & 3)) << 4);
    }

    const int sm = t & 127, cg = t >> 7;
    const int aswz = (sm >> 1) & 3;
    const int wo0 = (sm << 6) + (((cg * 2 + 0) ^ aswz) << 4);
    const int wo1 = (sm << 6) + (((cg * 2 + 1) ^ aswz) << 4);

    const int bcol = t >> 2;
    const size_t bgbase = (size_t)(colblk * 128 + bcol) * 768 + (t & 3) * 8;
    unsigned short* ldsBh0 = (unsigned short*)Bs_h + t * 8;
    unsigned short* ldsBh1 = (unsigned short*)Bs_h + 2048 + t * 8;
    unsigned short* ldsBl0 = (unsigned short*)Bs_l + t * 8;
    unsigned short* ldsBl1 = (unsigned short*)Bs_l + 2048 + t * 8;

    f32x4 acc[4][4];
    #pragma unroll
    for (int mi = 0; mi < 4; ++mi)
        #pragma unroll
        for (int ni = 0; ni < 4; ++ni) acc[mi][ni] = (f32x4){0.f, 0.f, 0.f, 0.f};

    #pragma unroll 1
    for (int kk = 0; kk < 24; ++kk) {
        const int cc = kk / 3;
        const int s = kk - cc * 3;
        const int kgl = s * 256 + cc * 32;

        glds16(Bh + bgbase + kgl, ldsBh0);
        glds16(Bh + bgbase + (size_t)64 * 768 + kgl, ldsBh1);
        glds16(Bl + bgbase + kgl, ldsBl0);
        glds16(Bl + bgbase + (size_t)64 * 768 + kgl, ldsBl1);

        const float* xc = xb + (((size_t)(cc * 32 + cg * 16)) << 12) + sm;
        #pragma unroll
        for (int half = 0; half < 2; ++half) {
            unsigned hw_[4], lw_[4];
            #pragma unroll
            for (int jp = 0; jp < 4; ++jp) {
                const float v0 = xc[(size_t)(half * 8 + jp * 2) << 12];
                const float v1 = xc[(size_t)(half * 8 + jp * 2 + 1) << 12];
                float p0 = v0, p1 = v1;
                if (s >= 1) { p0 *= v0; p1 *= v1; }
                if (s == 2) { p0 *= v0; p1 *= v1; }
                unsigned h0, l0, h1, l1;
                splitf16(p0, h0, l0);
                splitf16(p1, h1, l1);
                hw_[jp] = h0 | (h1 << 16);
                lw_[jp] = l0 | (l1 << 16);
            }
            const int wo = half ? wo1 : wo0;
            *(uint4*)(As_h + wo) = make_uint4(hw_[0], hw_[1], hw_[2], hw_[3]);
            *(uint4*)(As_l + wo) = make_uint4(lw_[0], lw_[1], lw_[2], lw_[3]);
        }
        __syncthreads();

        f16x8 vbh[4], vbl[4];
        #pragma unroll
        for (int ni = 0; ni < 4; ++ni) {
            vbh[ni] = *(const f16x8*)(Bs_h + boff[ni]);
            vbl[ni] = *(const f16x8*)(Bs_l + boff[ni]);
        }
        #pragma unroll
        for (int mi = 0; mi < 4; ++mi) {
            const f16x8 ah = *(const f16x8*)(As_h + aoff[mi]);
            const f16x8 al = *(const f16x8*)(As_l + aoff[mi]);
            #pragma unroll
            for (int ni = 0; ni < 4; ++ni) {
                acc[mi][ni] = MFMA(ah, vbh[ni], acc[mi][ni]);
                acc[mi][ni] = MFMA(al, vbh[ni], acc[mi][ni]);
                acc[mi][ni] = MFMA(ah, vbl[ni], acc[mi][ni]);
            }
        }
        __syncthreads();
    }

    const int colbase = colblk * 128 + wcol;
    float bs[4];
    #pragma unroll
    for (int ni = 0; ni < 4; ++ni) bs[ni] = bias[colbase + ni * 16 + lr];
    const int slot = colblk * 2 + (w & 1);
    #pragma unroll
    for (int mi = 0; mi < 4; ++mi) {
        #pragma unroll
        for (int r = 0; r < 4; ++r) {
            float bv = acc[mi][0][r] + bs[0];
            int bi = colbase + lr;
            #pragma unroll
            for (int ni = 1; ni < 4; ++ni) {
                const float v2 = acc[mi][ni][r] + bs[ni];
                if (v2 < bv) { bv = v2; bi = colbase + ni * 16 + lr; }
            }
            #pragma unroll
            for (int o = 1; o < 16; o <<= 1) {
                const float ov = __shfl_xor(bv, o, 64);
                const int oi = __shfl_xor(bi, o, 64);
                if (ov < bv || (ov == bv && oi < bi)) { bv = ov; bi = oi; }
            }
            if (lr == 0) {
                const int n = n0 + wrow + mi * 16 + lg * 4 + r;
                cval[slot * N_ROWS + n] = bv;
                cidx[slot * N_ROWS + n] = bi;
            }
        }
    }
}

// ---------------------------------------------------------------------------
__global__ void reduce_argmin(const float* __restrict__ cval, const int* __restrict__ cidx,
                              int* __restrict__ idx) {
    const int n = blockIdx.x * 256 + threadIdx.x;
    float bv = cval[n];
    int bi = cidx[n];
    #pragma unroll
    for (int s = 1; s < 16; ++s) {
        const float v = cval[s * N_ROWS + n];
        const int i = cidx[s * N_ROWS + n];
        if (v < bv || (v == bv && i < bi)) { bv = v; bi = i; }
    }
    idx[n] = bi;
}

// ---------------------------------------------------------------------------
__global__ void gather_out(const float* __restrict__ x, const float* __restrict__ embed,
                           const int* __restrict__ idx, float* __restrict__ out,
                           float* __restrict__ loss_accum) {
    const int gtid = blockIdx.x * 256 + threadIdx.x;
    float ls = 0.f;
    #pragma unroll
    for (int it = 0; it < 4; ++it) {
        const int tid = gtid + it * 1048576;
        const int g = tid << 2;
        const int bq = g >> 20;
        const int c = (g >> 12) & 255;
        const int hw = g & 4095;
        const int n = (bq << 12) | hw;

        const int4 id4 = *(const int4*)(idx + n);
        const float4 xv = *(const float4*)(x + g);
        float4 q;
        q.x = embed[id4.x * DIM + c];
        q.y = embed[id4.y * DIM + c];
        q.z = embed[id4.z * DIM + c];
        q.w = embed[id4.w * DIM + c];
        float4 d;
        d.x = q.x - xv.x; d.y = q.y - xv.y; d.z = q.z - xv.z; d.w = q.w - xv.w;
        float4 st;
        st.x = xv.x + d.x; st.y = xv.y + d.y; st.z = xv.z + d.z; st.w = xv.w + d.w;
        *(float4*)(out + g) = st;
        ls += d.x * d.x + d.y * d.y + d.z * d.z + d.w * d.w;
    }
    #pragma unroll
    for (int o = 32; o > 0; o >>= 1) ls += __shfl_down(ls, o, 64);
    __shared__ float ps[4];
    if ((threadIdx.x & 63) == 0) ps[threadIdx.x >> 6] = ls;
    __syncthreads();
    if (threadIdx.x == 0) atomicAdd(loss_accum, ps[0] + ps[1] + ps[2] + ps[3]);

    if (gtid < N_ROWS / 4) {
        const int4 iv = *(const int4*)(idx + (gtid << 2));
        float4 f;
        f.x = (float)iv.x; f.y = (float)iv.y; f.z = (float)iv.z; f.w = (float)iv.w;
        *(float4*)(out + Q_ELEMS + (gtid << 2)) = f;
    }
}

__global__ void finalize_loss(const float* __restrict__ loss_accum, float* __restrict__ out) {
    out[Q_ELEMS + N_ROWS] = COMMIT * (*loss_accum) / (float)Q_ELEMS;
}

// ---------------------------------------------------------------------------
extern "C" void kernel_launch(void* const* d_in, const int* in_sizes, int n_in,
                              void* d_out, int out_size, void* d_ws, size_t ws_size,
                              hipStream_t stream) {
    const float* x = (const float*)d_in[0];
    const float* embed = (const float*)d_in[1];
    char* ws = (char*)d_ws;
    unsigned short* Bh = (unsigned short*)(ws + OFF_BH);
    unsigned short* Bl = (unsigned short*)(ws + OFF_BL);
    float* bias = (float*)(ws + OFF_BIAS);
    float* cval = (float*)(ws + OFF_CVAL);
    int* cidx = (int*)(ws + OFF_CIDX);
    int* idx = (int*)(ws + OFF_IDX);
    float* lacc = (float*)(ws + OFF_LOSS);
    unsigned short* Ah = (unsigned short*)(ws + OFF_AH);
    unsigned short* Al = (unsigned short*)(ws + OFF_AL);
    float* out = (float*)d_out;

    hipLaunchKernelGGL(prep_embed, dim3(KCB), dim3(DIM), 0, stream, embed, Bh, Bl, bias, lacc);
    if (ws_size >= WS_NEED) {
        for (int p = 0; p < 4; ++p) {
            hipLaunchKernelGGL(convert_x, dim3(PASS_ROWS / 64), dim3(256), 0, stream,
                               x, p * PASS_ROWS, Ah, Al);
            hipLaunchKernelGGL(dist_mfma, dim3((PASS_ROWS / 128) * 8), dim3(256), 0, stream,
                               Ah, Al, Bh, Bl, bias, p * PASS_ROWS, cval, cidx);
        }
    } else {
        hipLaunchKernelGGL(dist_mfma_fb, dim3(4096), dim3(256), 0, stream,
                           x, Bh, Bl, bias, cval, cidx);
    }
    hipLaunchKernelGGL(reduce_argmin, dim3(N_ROWS / 256), dim3(256), 0, stream, cval, cidx, idx);
    hipLaunchKernelGGL(gather_out, dim3(4096), dim3(256), 0, stream, x, embed, idx, out, lacc);
    hipLaunchKernelGGL(finalize_loss, dim3(1), dim3(1), 0, stream, lacc, out);
}